// Round 1
// baseline (199.531 us; speedup 1.0000x reference)
//
#include <hip/hip_runtime.h>

#define F_EDGE 8
#define H 8

__device__ __forceinline__ unsigned short f2bf(float f) {
    unsigned u = __float_as_uint(f);
    unsigned r = u + 0x7fffu + ((u >> 16) & 1u);
    return (unsigned short)(r >> 16);
}
__device__ __forceinline__ float bflo(unsigned u) { return __uint_as_float(u << 16); }
__device__ __forceinline__ float bfhi(unsigned u) { return __uint_as_float(u & 0xffff0000u); }

// Per-node precompute for one NNConv layer, factorized:
//   Pt[n][j][k]   = sum_i feat[n][i] * We[k][i*H+j]   (stored bf16)
//   q[n][j]       = sum_i feat[n][i] * be[i*H+j]
//   aggseed[n][j] = b[j] + sum_i feat[n][i] * root[i*H+j]
// LDS holds a fused weight row per (i,j): [We k=0..7 | be | root | pad pad]
// so the inner loop is 2x ds_read_b128 + 1x ds_read_b64 per i (was 10x b32).
// INIT=true: block 0 additionally seeds out[g] = blast[0] (replaces the
// separate init_out_kernel dispatch).
template <int IN, bool RELU, bool INIT>
__global__ __launch_bounds__(256) void prep_kernel(
    const float* __restrict__ feat,       // [n_nodes, IN]
    const float* __restrict__ We,         // [F_EDGE, IN*H]
    const float* __restrict__ be,         // [IN*H]
    const float* __restrict__ root,       // [IN, H]
    const float* __restrict__ b,          // [H]
    unsigned short* __restrict__ Pt,      // [n_nodes, H, F_EDGE] bf16
    float* __restrict__ q,                // [n_nodes, H]
    float* __restrict__ aggseed,          // [n_nodes, H]
    int n_nodes,
    float* __restrict__ out, const float* __restrict__ blast, int out_n) {
    __shared__ float sW[IN * H * 12];
    int tid = threadIdx.x;
    for (int t = tid; t < IN * H * 12; t += 256) {
        int r = t / 12, m = t - r * 12;   // r = i*H + j
        float v = 0.f;
        if (m < 8) v = We[m * (IN * H) + r];
        else if (m == 8) v = be[r];
        else if (m == 9) v = root[r];
        sW[t] = v;
    }
    if (INIT && blockIdx.x == 0) {
        float bl = blast[0];
        for (int t = tid; t < out_n; t += 256) out[t] = bl;
    }
    __syncthreads();

    int n = blockIdx.x * 32 + (tid >> 3);
    if (n >= n_nodes) return;
    int j = tid & 7;

    float f[IN];
    const float4* fv = (const float4*)(feat + (long long)n * IN);
#pragma unroll
    for (int i4 = 0; i4 < IN / 4; ++i4) {
        float4 v = fv[i4];
        f[i4 * 4 + 0] = v.x; f[i4 * 4 + 1] = v.y;
        f[i4 * 4 + 2] = v.z; f[i4 * 4 + 3] = v.w;
    }
    if (RELU) {
#pragma unroll
        for (int i = 0; i < IN; ++i) f[i] = f[i] > 0.f ? f[i] : 0.f;
    }

    float p[8] = {0.f, 0.f, 0.f, 0.f, 0.f, 0.f, 0.f, 0.f};
    float qq = 0.f, hr = 0.f;
#pragma unroll
    for (int i = 0; i < IN; ++i) {
        const float* row = &sW[(i * 8 + j) * 12];
        float4 w0 = *(const float4*)row;
        float4 w1 = *(const float4*)(row + 4);
        float2 br = *(const float2*)(row + 8);
        float fi = f[i];
        p[0] = fmaf(fi, w0.x, p[0]); p[1] = fmaf(fi, w0.y, p[1]);
        p[2] = fmaf(fi, w0.z, p[2]); p[3] = fmaf(fi, w0.w, p[3]);
        p[4] = fmaf(fi, w1.x, p[4]); p[5] = fmaf(fi, w1.y, p[5]);
        p[6] = fmaf(fi, w1.z, p[6]); p[7] = fmaf(fi, w1.w, p[7]);
        qq = fmaf(fi, br.x, qq);
        hr = fmaf(fi, br.y, hr);
    }
    uint4 pw;
    pw.x = (unsigned)f2bf(p[0]) | ((unsigned)f2bf(p[1]) << 16);
    pw.y = (unsigned)f2bf(p[2]) | ((unsigned)f2bf(p[3]) << 16);
    pw.z = (unsigned)f2bf(p[4]) | ((unsigned)f2bf(p[5]) << 16);
    pw.w = (unsigned)f2bf(p[6]) | ((unsigned)f2bf(p[7]) << 16);
    *(uint4*)(Pt + ((long long)n * H + j) * F_EDGE) = pw;
    q[(long long)n * H + j] = qq;
    aggseed[(long long)n * H + j] = hr + b[j];
}

// Factorized edge kernel (both layers), 2 edges per thread for ILP:
//   msg_j = q[src][j] + sum_k ea[e][k] * Pt_bf16[src][j][k]
//   atomicAdd(agg[dst][j], msg_j)
// 8 lanes per edge; Pt row per lane is ONE 16B load (one cache line/edge).
// The kernel is latency-bound (VALUBusy 13%, HBM 25%): issuing both edges'
// dependent gather chains (ei -> Pt/q) back-to-back overlaps the ~2x
// ~300-900cy latency events that previously serialized per wave.
__global__ __launch_bounds__(256) void edge_fact_kernel(
    const int* __restrict__ ei,             // [2, E]
    const float* __restrict__ ea,           // [E, F_EDGE]
    const unsigned short* __restrict__ Pt,  // [n_nodes, H, F_EDGE] bf16
    const float* __restrict__ q,            // [n_nodes, H]
    float* __restrict__ agg,                // [n_nodes, H]
    int E) {
    int tid = threadIdx.x;
    int j = tid & 7;
    int eg = tid >> 3;                         // 0..31
    long long e0 = (long long)blockIdx.x * 64 + eg;
    if (e0 >= E) return;
    long long e1 = e0 + 32;
    bool has1 = (e1 < E);
    long long e1c = has1 ? e1 : e0;

    // Phase 1: independent index loads (both edges)
    int src0 = ei[e0];
    int src1 = ei[e1c];
    int dst0 = ei[E + e0];
    int dst1 = ei[E + e1c];

    // Phase 2: edge attrs (independent of src) + gathers (dependent)
    const float4* av0 = (const float4*)(ea + e0 * F_EDGE);
    const float4* av1 = (const float4*)(ea + e1c * F_EDGE);
    float4 a00 = av0[0], a01 = av0[1];
    float4 a10 = av1[0], a11 = av1[1];

    uint4 pw0 = *(const uint4*)(Pt + ((long long)src0 * H + j) * F_EDGE);
    uint4 pw1 = *(const uint4*)(Pt + ((long long)src1 * H + j) * F_EDGE);
    float m0 = q[(long long)src0 * H + j];
    float m1 = q[(long long)src1 * H + j];

    // Phase 3: compute both messages
    m0 = fmaf(a00.x, bflo(pw0.x), m0);
    m0 = fmaf(a00.y, bfhi(pw0.x), m0);
    m0 = fmaf(a00.z, bflo(pw0.y), m0);
    m0 = fmaf(a00.w, bfhi(pw0.y), m0);
    m0 = fmaf(a01.x, bflo(pw0.z), m0);
    m0 = fmaf(a01.y, bfhi(pw0.z), m0);
    m0 = fmaf(a01.z, bflo(pw0.w), m0);
    m0 = fmaf(a01.w, bfhi(pw0.w), m0);

    m1 = fmaf(a10.x, bflo(pw1.x), m1);
    m1 = fmaf(a10.y, bfhi(pw1.x), m1);
    m1 = fmaf(a10.z, bflo(pw1.y), m1);
    m1 = fmaf(a10.w, bfhi(pw1.y), m1);
    m1 = fmaf(a11.x, bflo(pw1.z), m1);
    m1 = fmaf(a11.y, bfhi(pw1.z), m1);
    m1 = fmaf(a11.z, bflo(pw1.w), m1);
    m1 = fmaf(a11.w, bfhi(pw1.w), m1);

    // Phase 4: fire-and-forget atomics
    unsafeAtomicAdd(&agg[(long long)dst0 * H + j], m0);
    if (has1) unsafeAtomicAdd(&agg[(long long)dst1 * H + j], m1);
}

// Pool: per-block LDS bins (batch is sorted -> few hot bins per block),
// then one global atomic per nonzero bin.
__global__ __launch_bounds__(256) void pool_kernel(
    const float* __restrict__ h2pre, const int* __restrict__ batch,
    const float* __restrict__ Wlast, float* __restrict__ out,
    int n_nodes, int n_graphs) {
    __shared__ float bins[512];
    bool use_bins = (n_graphs <= 512);
    if (use_bins) {
        for (int t = threadIdx.x; t < n_graphs; t += 256) bins[t] = 0.f;
        __syncthreads();
    }
    float wl[8];
#pragma unroll
    for (int j = 0; j < 8; ++j) wl[j] = Wlast[j];

    int base = blockIdx.x * 1024;
#pragma unroll
    for (int r = 0; r < 4; ++r) {
        int n = base + r * 256 + threadIdx.x;
        if (n < n_nodes) {
            const float4* hv = (const float4*)(h2pre + (long long)n * H);
            float4 h0 = hv[0], h1 = hv[1];
            float c = 0.f;
            c = fmaf(fmaxf(h0.x, 0.f), wl[0], c);
            c = fmaf(fmaxf(h0.y, 0.f), wl[1], c);
            c = fmaf(fmaxf(h0.z, 0.f), wl[2], c);
            c = fmaf(fmaxf(h0.w, 0.f), wl[3], c);
            c = fmaf(fmaxf(h1.x, 0.f), wl[4], c);
            c = fmaf(fmaxf(h1.y, 0.f), wl[5], c);
            c = fmaf(fmaxf(h1.z, 0.f), wl[6], c);
            c = fmaf(fmaxf(h1.w, 0.f), wl[7], c);
            if (use_bins) atomicAdd(&bins[batch[n]], c);
            else unsafeAtomicAdd(&out[batch[n]], c);
        }
    }
    if (use_bins) {
        __syncthreads();
        for (int t = threadIdx.x; t < n_graphs; t += 256) {
            float v = bins[t];
            if (v != 0.f) unsafeAtomicAdd(&out[t], v);
        }
    }
}

extern "C" void kernel_launch(void* const* d_in, const int* in_sizes, int n_in,
                              void* d_out, int out_size, void* d_ws, size_t ws_size,
                              hipStream_t stream) {
    const float* x     = (const float*)d_in[0];
    const int*   ei    = (const int*)d_in[1];
    const float* ea    = (const float*)d_in[2];
    const int*   batch = (const int*)d_in[3];
    const float* We1   = (const float*)d_in[4];
    const float* be1   = (const float*)d_in[5];
    const float* root1 = (const float*)d_in[6];
    const float* b1    = (const float*)d_in[7];
    const float* We2   = (const float*)d_in[8];
    const float* be2   = (const float*)d_in[9];
    const float* root2 = (const float*)d_in[10];
    const float* b2    = (const float*)d_in[11];
    const float* Wlast = (const float*)d_in[12];
    const float* blast = (const float*)d_in[13];
    float* out = (float*)d_out;

    int F_IN_rt = 16;
    int n_nodes = in_sizes[0] / F_IN_rt;
    int E = in_sizes[1] / 2;

    size_t nH = (size_t)n_nodes * H;
    unsigned short* Pt1 = (unsigned short*)d_ws;          // n*64 bf16
    unsigned short* Pt2 = Pt1 + (size_t)n_nodes * H * F_EDGE;
    float* q1    = (float*)(Pt2 + (size_t)n_nodes * H * F_EDGE);
    float* q2    = q1 + nH;
    float* h1pre = q2 + nH;
    float* h2pre = h1pre + nH;

    int nblocks = (n_nodes + 31) / 32;
    // prep1 also seeds out[g] = blast[0] (block 0), replacing init_out_kernel
    prep_kernel<16, false, true><<<nblocks, 256, 0, stream>>>(
        x, We1, be1, root1, b1, Pt1, q1, h1pre, n_nodes, out, blast, out_size);

    int eblks = (E + 63) / 64;   // 64 edges/block, 2 edges/thread
    edge_fact_kernel<<<eblks, 256, 0, stream>>>(ei, ea, Pt1, q1, h1pre, E);

    prep_kernel<H, true, false><<<nblocks, 256, 0, stream>>>(
        h1pre, We2, be2, root2, b2, Pt2, q2, h2pre, n_nodes, nullptr, nullptr, 0);

    edge_fact_kernel<<<eblks, 256, 0, stream>>>(ei, ea, Pt2, q2, h2pre, E);

    int pblocks = (n_nodes + 1023) / 1024;
    pool_kernel<<<pblocks, 256, 0, stream>>>(h2pre, batch, Wlast, out, n_nodes, out_size);
}